// Round 8
// baseline (164.157 us; speedup 1.0000x reference)
//
#include <hip/hip_runtime.h>

#define NB 8
#define TAPS 5

template<int NW>
__device__ __forceinline__ void loadrow(const float* __restrict__ p, float* w) {
#pragma unroll
    for (int c = 0; c < NW / 4; ++c)
        *reinterpret_cast<float4*>(w + 4 * c) = *reinterpret_cast<const float4*>(p + 4 * c);
}

// Vertical synthesis for one plane-pair over an NW-wide 16B-aligned window.
// a0[k] = sum_t hk0[t]*A[n-2+t][k+OFF] + gk0[t]*B[n-2+t][k+OFF]; a1 with hk1/gk1.
// Row antireflect handled by loading edge/reflected rows as data.
template<int NW, int OFF>
__device__ __forceinline__ void vert2(const float* __restrict__ A, const float* __restrict__ B,
                                      int n, int N,
                                      const float* hk0, const float* hk1,
                                      const float* gk0, const float* gk1,
                                      float a0[8], float a1[8]) {
#pragma unroll
    for (int k = 0; k < 8; ++k) { a0[k] = 0.f; a1[k] = 0.f; }
    if (n >= 2 && n <= N - 3) {          // wave-uniform (jc-major thread layout)
#pragma unroll
        for (int t = 0; t < TAPS; ++t) {
            float wa[NW], wb[NW];
            loadrow<NW>(A + (size_t)(n - 2 + t) * N, wa);
            loadrow<NW>(B + (size_t)(n - 2 + t) * N, wb);
#pragma unroll
            for (int k = 0; k < 8; ++k) {
                a0[k] += hk0[t] * wa[k + OFF] + gk0[t] * wb[k + OFF];
                a1[k] += hk1[t] * wa[k + OFF] + gk1[t] * wb[k + OFF];
            }
        }
    } else {
#pragma unroll
        for (int t = 0; t < TAPS; ++t) {
            const int m = n - 2 + t;
            float wa[NW], wb[NW];
            if ((unsigned)m < (unsigned)N) {
                loadrow<NW>(A + (size_t)m * N, wa);
                loadrow<NW>(B + (size_t)m * N, wb);
            } else {
                const int e  = (m < 0) ? 0 : N - 1;
                const int rr = (m < 0) ? -m : 2 * (N - 1) - m;
                float ea[NW], eb[NW], ra[NW], rb[NW];
                loadrow<NW>(A + (size_t)e * N, ea);
                loadrow<NW>(B + (size_t)e * N, eb);
                loadrow<NW>(A + (size_t)rr * N, ra);
                loadrow<NW>(B + (size_t)rr * N, rb);
#pragma unroll
                for (int k = 0; k < NW; ++k) {
                    wa[k] = 2.f * ea[k] - ra[k];
                    wb[k] = 2.f * eb[k] - rb[k];
                }
            }
#pragma unroll
            for (int k = 0; k < 8; ++k) {
                a0[k] += hk0[t] * wa[k + OFF] + gk0[t] * wb[k + OFF];
                a1[k] += hk1[t] * wa[k + OFF] + gk1[t] * wb[k + OFF];
            }
        }
    }
}

// column antireflect remaps (post-vertical, exact by linearity)
__device__ __forceinline__ void remap_left(float A[8]) {
    const float o0 = A[0], o1 = A[1], o2 = A[2];
#pragma unroll
    for (int k = 7; k >= 2; --k) A[k] = A[k - 2];
    A[1] = 2.f * o0 - o1;
    A[0] = 2.f * o0 - o2;
}
__device__ __forceinline__ void remap_right(float A[8]) {
    const float o5 = A[5], o6 = A[6], o7 = A[7];
#pragma unroll
    for (int k = 0; k < 6; ++k) A[k] = A[k + 2];
    A[6] = 2.f * o7 - o6;
    A[7] = 2.f * o7 - o5;
}

__global__ __launch_bounds__(256, 7)
void idwt_direct(const float* __restrict__ Pss, const float* __restrict__ Psd,
                 const float* __restrict__ Pds, const float* __restrict__ Pdd,
                 const float* __restrict__ h, const float* __restrict__ g_,
                 float* __restrict__ out, int N) {
    const int NJ = N >> 2;
    const int total = NB * N * NJ;
    const int tid = blockIdx.x * blockDim.x + threadIdx.x;
    if (tid >= total) return;
    const int jc = tid % NJ;
    const int rest = tid / NJ;
    const int n = rest % N;
    const int b = rest / N;

    float hk0[TAPS], hk1[TAPS], gk0[TAPS], gk1[TAPS];   // uniform -> SGPRs
#pragma unroll
    for (int t = 0; t < TAPS; ++t) {
        hk0[t] = h[8 - 2 * t];  hk1[t] = h[9 - 2 * t];
        gk0[t] = g_[8 - 2 * t]; gk1[t] = g_[9 - 2 * t];
    }

    const size_t plane = (size_t)N * N;
    const float* A  = Pss + (size_t)b * plane;
    const float* Bq = Psd + (size_t)b * plane;
    const float* C  = Pds + (size_t)b * plane;
    const float* D  = Pdd + (size_t)b * plane;

    float s0[8], s1[8], d0[8], d1[8];
    if (jc >= 1 && jc <= NJ - 2) {
        const int cb = 4 * jc - 4;      // aligned window [cb, cb+12), use [2..9]
        vert2<12, 2>(A + cb, Bq + cb, n, N, hk0, hk1, gk0, gk1, s0, s1);
        vert2<12, 2>(C + cb, D + cb,  n, N, hk0, hk1, gk0, gk1, d0, d1);
    } else if (jc == 0) {
        vert2<8, 0>(A, Bq, n, N, hk0, hk1, gk0, gk1, s0, s1);
        vert2<8, 0>(C, D,  n, N, hk0, hk1, gk0, gk1, d0, d1);
        remap_left(s0); remap_left(s1); remap_left(d0); remap_left(d1);
    } else {                            // jc == NJ-1
        const int cb = N - 8;
        vert2<8, 0>(A + cb, Bq + cb, n, N, hk0, hk1, gk0, gk1, s0, s1);
        vert2<8, 0>(C + cb, D + cb,  n, N, hk0, hk1, gk0, gk1, d0, d1);
        remap_right(s0); remap_right(s1); remap_right(d0); remap_right(d1);
    }

    // horizontal synthesis: 4 output pairs x 2 rows
    const int M = 2 * N;
    float oa[8], ob[8];
#pragma unroll
    for (int cc = 0; cc < 4; ++cc) {
        float x0 = 0.f, x1 = 0.f, y0 = 0.f, y1 = 0.f;
#pragma unroll
        for (int t = 0; t < TAPS; ++t) {
            const float sA = s0[cc + t], dA = d0[cc + t];
            const float sB = s1[cc + t], dB = d1[cc + t];
            x0 += hk0[t] * sA + gk0[t] * dA;
            x1 += hk1[t] * sA + gk1[t] * dA;
            y0 += hk0[t] * sB + gk0[t] * dB;
            y1 += hk1[t] * sB + gk1[t] * dB;
        }
        oa[2 * cc] = x0; oa[2 * cc + 1] = x1;
        ob[2 * cc] = y0; ob[2 * cc + 1] = y1;
    }

    float* dst0 = out + ((size_t)b * M + 2 * n) * M + 8 * jc;
    float* dst1 = dst0 + M;
    *reinterpret_cast<float4*>(dst0)     = make_float4(oa[0], oa[1], oa[2], oa[3]);
    *reinterpret_cast<float4*>(dst0 + 4) = make_float4(oa[4], oa[5], oa[6], oa[7]);
    *reinterpret_cast<float4*>(dst1)     = make_float4(ob[0], ob[1], ob[2], ob[3]);
    *reinterpret_cast<float4*>(dst1 + 4) = make_float4(ob[4], ob[5], ob[6], ob[7]);
}

extern "C" void kernel_launch(void* const* d_in, const int* in_sizes, int n_in,
                              void* d_out, int out_size, void* d_ws, size_t ws_size,
                              hipStream_t stream) {
    const float* ss = (const float*)d_in[0];
    const float* sd[3] = {(const float*)d_in[1], (const float*)d_in[2], (const float*)d_in[3]};
    const float* ds[3] = {(const float*)d_in[4], (const float*)d_in[5], (const float*)d_in[6]};
    const float* dd[3] = {(const float*)d_in[7], (const float*)d_in[8], (const float*)d_in[9]};
    const float* h = (const float*)d_in[10];
    const float* g = (const float*)d_in[11];
    float* out = (float*)d_out;

    char* ws = (char*)d_ws;
    float* I0 = (float*)ws;                        // level-2 output (2 MiB)
    float* I1 = (float*)(ws + ((size_t)2 << 20));  // level-1 output (8 MiB)

    auto launch = [&](const float* a, const float* sdp, const float* dsp, const float* ddp,
                      float* dst, int N) {
        const int total = NB * N * (N >> 2);
        idwt_direct<<<(total + 255) / 256, 256, 0, stream>>>(a, sdp, dsp, ddp, h, g, dst, N);
    };

    launch(ss, sd[2], ds[2], dd[2], I0, 128);   // level 2: 128 -> 256
    launch(I0, sd[1], ds[1], dd[1], I1, 256);   // level 1: 256 -> 512
    launch(I1, sd[0], ds[0], dd[0], out, 512);  // level 0: 512 -> 1024
}

// Round 9
// 41.710 us; speedup vs baseline: 3.9356x; 3.9356x over previous
//
#include <hip/hip_runtime.h>

#define NB 8
#define TAPS 5

// load 8-col window (8B-aligned) via 4x float2
__device__ __forceinline__ void ldw8(const float* __restrict__ p, float* w) {
#pragma unroll
    for (int k = 0; k < 4; ++k) {
        const float2 v = *reinterpret_cast<const float2*>(p + 2 * k);
        w[2 * k] = v.x; w[2 * k + 1] = v.y;
    }
}

// column antireflect remaps (post-vertical, exact by linearity)
__device__ __forceinline__ void remap_left(float A[8]) {
    const float o0 = A[0], o1 = A[1], o2 = A[2];
#pragma unroll
    for (int k = 7; k >= 2; --k) A[k] = A[k - 2];
    A[1] = 2.f * o0 - o1;
    A[0] = 2.f * o0 - o2;
}
__device__ __forceinline__ void remap_right(float A[8]) {
    const float o5 = A[5], o6 = A[6], o7 = A[7];
#pragma unroll
    for (int k = 0; k < 6; ++k) A[k] = A[k + 2];
    A[6] = 2.f * o7 - o6;
    A[7] = 2.f * o7 - o5;
}

__device__ __forceinline__ void horiz(const float s0[8], const float s1[8],
                                      const float d0[8], const float d1[8],
                                      const float* hk0, const float* hk1,
                                      const float* gk0, const float* gk1,
                                      float oa[8], float ob[8]) {
#pragma unroll
    for (int cc = 0; cc < 4; ++cc) {
        float x0 = 0.f, x1 = 0.f, y0 = 0.f, y1 = 0.f;
#pragma unroll
        for (int t = 0; t < TAPS; ++t) {
            x0 += hk0[t] * s0[cc + t] + gk0[t] * d0[cc + t];
            x1 += hk1[t] * s0[cc + t] + gk1[t] * d0[cc + t];
            y0 += hk0[t] * s1[cc + t] + gk0[t] * d1[cc + t];
            y1 += hk1[t] * s1[cc + t] + gk1[t] * d1[cc + t];
        }
        oa[2 * cc] = x0; oa[2 * cc + 1] = x1;
        ob[2 * cc] = y0; ob[2 * cc + 1] = y1;
    }
}

// Thread = (b, coarse-row pair n0=2g,n0+1, 4 coarse cols) -> 4x8 output patch.
// 6 input rows feed both output row-pairs (vertical reuse in registers).
// XCD-aware block swizzle: each XCD gets a contiguous (b, g) chunk -> row-halo
// reuse hits the local L2 instead of being duplicated across XCDs.
__global__ __launch_bounds__(256)
void idwt_direct2(const float* __restrict__ Pss, const float* __restrict__ Psd,
                  const float* __restrict__ Pds, const float* __restrict__ Pdd,
                  const float* __restrict__ h, const float* __restrict__ g_,
                  float* __restrict__ out, int N) {
    const int NJ = N >> 2;
    const int G2 = N >> 1;

    // XCD swizzle (all grids here are multiples of 8; guard anyway)
    const int nwg = gridDim.x;
    const int hw  = blockIdx.x;
    const int lb  = (nwg & 7) ? hw : ((hw & 7) * (nwg >> 3) + (hw >> 3));
    const int tid = lb * 256 + threadIdx.x;

    const int jc = tid % NJ;
    const int rest = tid / NJ;
    const int g = rest % G2;
    const int b = rest / G2;
    const int n0 = 2 * g;

    float hk0[TAPS], hk1[TAPS], gk0[TAPS], gk1[TAPS];   // uniform
#pragma unroll
    for (int t = 0; t < TAPS; ++t) {
        hk0[t] = h[8 - 2 * t];  hk1[t] = h[9 - 2 * t];
        gk0[t] = g_[8 - 2 * t]; gk1[t] = g_[9 - 2 * t];
    }

    const size_t plane = (size_t)N * N;
    const float* A  = Pss + (size_t)b * plane;
    const float* Bq = Psd + (size_t)b * plane;
    const float* C  = Pds + (size_t)b * plane;
    const float* D  = Pdd + (size_t)b * plane;

    // clamped column window: logical cols jb..jb+7, physical base..base+7
    const int jb = 4 * jc - 2;
    int base = jb;
    if (base < 0) base = 0;
    if (base > N - 8) base = N - 8;

    float sA0[8], sA1[8], dA0[8], dA1[8];   // outputs of n0
    float sB0[8], sB1[8], dB0[8], dB1[8];   // outputs of n0+1
#pragma unroll
    for (int k = 0; k < 8; ++k) {
        sA0[k] = sA1[k] = dA0[k] = dA1[k] = 0.f;
        sB0[k] = sB1[k] = dB0[k] = dB1[k] = 0.f;
    }

    // ---- vertical synthesis: 6 shared rows, row antireflect as data
#pragma unroll
    for (int r = 0; r < 6; ++r) {
        const int m = n0 - 2 + r;
        float wa[8], wb[8], wc[8], wd[8];
        if ((unsigned)m < (unsigned)N) {
            const size_t o = (size_t)m * N + base;
            ldw8(A + o, wa); ldw8(Bq + o, wb); ldw8(C + o, wc); ldw8(D + o, wd);
        } else {
            const int e  = (m < 0) ? 0 : N - 1;
            const int rr = (m < 0) ? -m : 2 * (N - 1) - m;
            const size_t oe = (size_t)e * N + base;
            const size_t orf = (size_t)rr * N + base;
            float ea[8], ra[8];
            ldw8(A + oe, ea);  ldw8(A + orf, ra);
#pragma unroll
            for (int k = 0; k < 8; ++k) wa[k] = 2.f * ea[k] - ra[k];
            ldw8(Bq + oe, ea); ldw8(Bq + orf, ra);
#pragma unroll
            for (int k = 0; k < 8; ++k) wb[k] = 2.f * ea[k] - ra[k];
            ldw8(C + oe, ea);  ldw8(C + orf, ra);
#pragma unroll
            for (int k = 0; k < 8; ++k) wc[k] = 2.f * ea[k] - ra[k];
            ldw8(D + oe, ea);  ldw8(D + orf, ra);
#pragma unroll
            for (int k = 0; k < 8; ++k) wd[k] = 2.f * ea[k] - ra[k];
        }
        if (r < 5) {          // n0 uses taps t=r
#pragma unroll
            for (int k = 0; k < 8; ++k) {
                sA0[k] += hk0[r] * wa[k] + gk0[r] * wb[k];
                sA1[k] += hk1[r] * wa[k] + gk1[r] * wb[k];
                dA0[k] += hk0[r] * wc[k] + gk0[r] * wd[k];
                dA1[k] += hk1[r] * wc[k] + gk1[r] * wd[k];
            }
        }
        if (r >= 1) {         // n0+1 uses taps t=r-1
            const int t = r - 1;
#pragma unroll
            for (int k = 0; k < 8; ++k) {
                sB0[k] += hk0[t] * wa[k] + gk0[t] * wb[k];
                sB1[k] += hk1[t] * wa[k] + gk1[t] * wb[k];
                dB0[k] += hk0[t] * wc[k] + gk0[t] * wd[k];
                dB1[k] += hk1[t] * wc[k] + gk1[t] * wd[k];
            }
        }
    }

    // ---- column antireflect remap (edge strips only)
    if (jb < 0) {
        remap_left(sA0); remap_left(sA1); remap_left(dA0); remap_left(dA1);
        remap_left(sB0); remap_left(sB1); remap_left(dB0); remap_left(dB1);
    } else if (jb > base) {
        remap_right(sA0); remap_right(sA1); remap_right(dA0); remap_right(dA1);
        remap_right(sB0); remap_right(sB1); remap_right(dB0); remap_right(dB1);
    }

    // ---- horizontal synthesis + stores (4 output rows x 8 cols)
    const int M = 2 * N;
    float oa[8], ob[8];
    float* dst = out + ((size_t)b * M + 4 * g) * M + 8 * jc;

    horiz(sA0, sA1, dA0, dA1, hk0, hk1, gk0, gk1, oa, ob);
    *reinterpret_cast<float4*>(dst)         = make_float4(oa[0], oa[1], oa[2], oa[3]);
    *reinterpret_cast<float4*>(dst + 4)     = make_float4(oa[4], oa[5], oa[6], oa[7]);
    *reinterpret_cast<float4*>(dst + M)     = make_float4(ob[0], ob[1], ob[2], ob[3]);
    *reinterpret_cast<float4*>(dst + M + 4) = make_float4(ob[4], ob[5], ob[6], ob[7]);

    horiz(sB0, sB1, dB0, dB1, hk0, hk1, gk0, gk1, oa, ob);
    dst += 2 * (size_t)M;
    *reinterpret_cast<float4*>(dst)         = make_float4(oa[0], oa[1], oa[2], oa[3]);
    *reinterpret_cast<float4*>(dst + 4)     = make_float4(oa[4], oa[5], oa[6], oa[7]);
    *reinterpret_cast<float4*>(dst + M)     = make_float4(ob[0], ob[1], ob[2], ob[3]);
    *reinterpret_cast<float4*>(dst + M + 4) = make_float4(ob[4], ob[5], ob[6], ob[7]);
}

extern "C" void kernel_launch(void* const* d_in, const int* in_sizes, int n_in,
                              void* d_out, int out_size, void* d_ws, size_t ws_size,
                              hipStream_t stream) {
    const float* ss = (const float*)d_in[0];
    const float* sd[3] = {(const float*)d_in[1], (const float*)d_in[2], (const float*)d_in[3]};
    const float* ds[3] = {(const float*)d_in[4], (const float*)d_in[5], (const float*)d_in[6]};
    const float* dd[3] = {(const float*)d_in[7], (const float*)d_in[8], (const float*)d_in[9]};
    const float* h = (const float*)d_in[10];
    const float* g = (const float*)d_in[11];
    float* out = (float*)d_out;

    char* ws = (char*)d_ws;
    float* I0 = (float*)ws;                        // level-2 output (2 MiB)
    float* I1 = (float*)(ws + ((size_t)2 << 20));  // level-1 output (8 MiB)

    auto launch = [&](const float* a, const float* sdp, const float* dsp, const float* ddp,
                      float* dst, int N) {
        const int total = NB * (N >> 1) * (N >> 2);   // threads: b x g x jc
        idwt_direct2<<<(total + 255) / 256, 256, 0, stream>>>(a, sdp, dsp, ddp, h, g, dst, N);
    };

    launch(ss, sd[2], ds[2], dd[2], I0, 128);   // level 2: 128 -> 256
    launch(I0, sd[1], ds[1], dd[1], I1, 256);   // level 1: 256 -> 512
    launch(I1, sd[0], ds[0], dd[0], out, 512);  // level 0: 512 -> 1024
}